// Round 11
// baseline (216.243 us; speedup 1.0000x reference)
//
#include <hip/hip_runtime.h>
#include <cstdint>
#include <cstddef>

#define BN 16
#define HH 480
#define WW 640
#define HWSZ (HH*WW)
#define CAP 32768
#define TOPK 512
#define RED_BLOCKS 2048
#define NTX 128
#define NTY 32

typedef unsigned long long u64;

// ---- workspace layout (bytes) ----
#define W2_OFF   0ULL
#define W2_SZ    ((unsigned long long)BN*HWSZ*4ULL)            // 19,660,800
#define MAPS_OFF (W2_OFF + W2_SZ)
#define MAPS_SZ  (2ULL*BN*HWSZ*4ULL)                           // 39,321,600
#define CAND_OFF (MAPS_OFF + MAPS_SZ)
#define CAND_SZ  (2ULL*BN*CAP*8ULL)                            // 8,388,608
#define CNT_OFF  (CAND_OFF + CAND_SZ)
#define CNT_SZ   (4096ULL)                                     // 32 counters, 128B apart
#define SEL_OFF  (CNT_OFF + CNT_SZ)
#define SEL_SZ   (2ULL*BN*TOPK*8ULL)                           // 131,072
#define PART_OFF (SEL_OFF + SEL_SZ)
#define PART_SZ  ((unsigned long long)RED_BLOCKS*2*4ULL)       // 16,384

// ============ kernel 1: warp score2 (border-filtered) + visibility ============
// 4 px/thread; per-pixel math identical to the verified scalar version.
// Block 0 also zeroes the cnt[] counters (replaces a memset dispatch; k_nms
// launches strictly after this kernel completes).
__global__ void k_warp_vis(const float* __restrict__ score2,
                           const float* __restrict__ homo,
                           float* __restrict__ w2,
                           float* __restrict__ vis,
                           unsigned int* __restrict__ cnt) {
    if (blockIdx.x == 0) {
        for (int i = threadIdx.x; i < 1024; i += 256) cnt[i] = 0u;
    }
    int t = blockIdx.x * 256 + threadIdx.x;            // < BN*HWSZ/4
    int b = t / (HWSZ / 4);
    int q = t - b * (HWSZ / 4);
    int p = q * 4;                                     // 4-aligned, same row (WW%4==0)
    int py = p / WW, px = p - py * WW;
    const float* h = homo + b * 9;
    const float* sb = score2 + (size_t)b * HWSZ;

    float4 wout;
    float vout[4];
    #pragma unroll
    for (int u = 0; u < 4; ++u) {
        float fx = (float)(px + u), fy = (float)py;
        float X = h[0] * fx + h[1] * fy + h[2];
        float Y = h[3] * fx + h[4] * fy + h[5];
        float Z = h[6] * fx + h[7] * fy + h[8];
        float x = X / Z, y = Y / Z;
        float x0 = floorf(x), y0 = floorf(y);
        float wx = x - x0, wy = y - y0;
        float vv[4], gv[4];
        #pragma unroll
        for (int j = 0; j < 2; ++j) {
            #pragma unroll
            for (int i = 0; i < 2; ++i) {
                float xx = x0 + (float)i;
                float yy = y0 + (float)j;
                bool valid = (xx >= 0.f) && (xx <= (float)(WW - 1)) &&
                             (yy >= 0.f) && (yy <= (float)(HH - 1));
                int xi = (int)fminf(fmaxf(xx, 0.f), (float)(WW - 1));
                int yi = (int)fminf(fmaxf(yy, 0.f), (float)(HH - 1));
                float v = sb[yi * WW + xi];
                bool inb = (xi >= 8) && (xi < WW - 8) && (yi >= 8) && (yi < HH - 8);
                vv[j * 2 + i] = (valid && inb) ? v : 0.f;
                gv[j * 2 + i] = valid ? 1.f : 0.f;
            }
        }
        float w00 = (1.f - wy) * (1.f - wx), w01 = (1.f - wy) * wx;
        float w10 = wy * (1.f - wx),         w11 = wy * wx;
        float val = w00 * vv[0] + w01 * vv[1] + w10 * vv[2] + w11 * vv[3];
        float vsm = w00 * gv[0] + w01 * gv[1] + w10 * gv[2] + w11 * gv[3];
        ((float*)&wout)[u] = val;
        vout[u] = (vsm > 0.f) ? 1.f : 0.f;
    }
    int base = b * HWSZ + p;
    *reinterpret_cast<float4*>(w2 + base) = wout;      // w2 16B-aligned in ws
    // vis points into d_out at 4-mod-16 byte offset -> scalar stores
    vis[base + 0] = vout[0];
    vis[base + 1] = vout[1];
    vis[base + 2] = vout[2];
    vis[base + 3] = vout[3];
}

// ============ kernel 2: 5x5 NMS, 128x32 tile, separable max, 16 out/thread ==
// z in [0,32): z<16 -> score1 image z; z>=16 -> w2 image z-16
__global__ void k_nms(const float* __restrict__ s1,
                      const float* __restrict__ w2,
                      u64* __restrict__ cand,
                      unsigned int* __restrict__ cnt) {
    __shared__ float tile[NTY + 4][NTX + 4];     // 36 x 132 = 19,008 B
    __shared__ float colmax[NTY][NTX + 4];       // 32 x 132 = 16,896 B
    __shared__ unsigned int s_loc, s_base;
    int z = blockIdx.z;
    const float* sb = (z < BN) ? (s1 + (size_t)z * HWSZ)
                               : (w2 + (size_t)(z - BN) * HWSZ);
    int tid = threadIdx.x;
    int bx0 = blockIdx.x * NTX, by0 = blockIdx.y * NTY;
    if (tid == 0) s_loc = 0;

    for (int i = tid; i < (NTY + 4) * (NTX + 4); i += 256) {
        int ly = i / (NTX + 4), lx = i - ly * (NTX + 4);
        int gy = by0 + ly - 2, gx = bx0 + lx - 2;
        float v = -__builtin_inff();
        if ((unsigned)gy < (unsigned)HH && (unsigned)gx < (unsigned)WW)
            v = sb[gy * WW + gx];
        tile[ly][lx] = v;
    }
    __syncthreads();

    // column max over 5 rows
    for (int i = tid; i < NTY * (NTX + 4); i += 256) {
        int y = i / (NTX + 4), x = i - y * (NTX + 4);
        float m = tile[y][x];
        m = fmaxf(m, tile[y + 1][x]);
        m = fmaxf(m, tile[y + 2][x]);
        m = fmaxf(m, tile[y + 3][x]);
        m = fmaxf(m, tile[y + 4][x]);
        colmax[y][x] = m;
    }
    __syncthreads();

    int ox = tid & 127, oyb = (tid >> 7) * 16;   // 2 col-groups x 16 rows
    bool fl[16];
    float vv[16];
    unsigned int pos[16];
    #pragma unroll
    for (int k = 0; k < 16; ++k) {
        int oy = oyb + k;
        float v = tile[oy + 2][ox + 2];
        float m = colmax[oy][ox];
        m = fmaxf(m, colmax[oy][ox + 1]);
        m = fmaxf(m, colmax[oy][ox + 2]);
        m = fmaxf(m, colmax[oy][ox + 3]);
        m = fmaxf(m, colmax[oy][ox + 4]);
        fl[k] = (v == m) && (v > 0.f);
        vv[k] = v;
        if (fl[k]) pos[k] = atomicAdd(&s_loc, 1u);
    }
    __syncthreads();
    if (tid == 0 && s_loc) s_base = atomicAdd(&cnt[z * 32], s_loc);
    __syncthreads();
    #pragma unroll
    for (int k = 0; k < 16; ++k) {
        if (fl[k]) {
            unsigned int off = s_base + pos[k];
            if (off < CAP) {
                int p = (by0 + oyb + k) * WW + bx0 + ox;
                cand[(size_t)z * CAP + off] =
                    ((u64)__float_as_uint(vv[k]) << 32) | (u64)(~(unsigned)p);
            }
        }
    }
}

// ============ kernel 3: radix-select top-512; m==0 blocks also sort + emit kp
__global__ __launch_bounds__(1024) void k_topk(const u64* __restrict__ cand,
                                               const unsigned int* __restrict__ cnt,
                                               u64* __restrict__ sel,
                                               float* __restrict__ kp_out) {
    int s = blockIdx.x;                 // 0..31 : m = s>>4, b = s&15
    int tid = threadIdx.x;              // 1024 threads
    int n = (int)cnt[s * 32];
    if (n > CAP) n = CAP;
    const u64* keys = cand + (size_t)s * CAP;

    __shared__ unsigned int histw[16][256];   // per-wave histograms
    __shared__ unsigned int hist[256];
    __shared__ u64 skeys[TOPK];
    __shared__ int s_digit, s_krem, s_done;
    __shared__ unsigned int s_cnt;

    int wid = tid >> 6;

    if (n > TOPK) {
        u64 prefix = 0ULL;
        int krem = TOPK;
        for (int lvl = 7; lvl >= 0; --lvl) {
            for (int i = tid; i < 16 * 256; i += 1024) ((unsigned int*)histw)[i] = 0u;
            if (tid == 0) s_done = 0;
            __syncthreads();
            int shift = lvl * 8;
            u64 pmask = (lvl == 7) ? 0ULL : (~0ULL << (shift + 8));
            for (int i = tid; i < n; i += 1024) {
                u64 k = keys[i];
                if ((k & pmask) == prefix)
                    atomicAdd(&histw[wid][(unsigned int)((k >> shift) & 0xFF)], 1u);
            }
            __syncthreads();
            if (tid < 256) {
                unsigned int sum = 0;
                #pragma unroll
                for (int w = 0; w < 16; ++w) sum += histw[w][tid];
                hist[tid] = sum;
            }
            __syncthreads();
            // inclusive suffix-sum: hist[v] = count of digits >= v
            for (int off = 1; off < 256; off <<= 1) {
                unsigned int add = 0;
                if (tid < 256 - off) add = hist[tid + off];
                __syncthreads();
                if (tid < 256) hist[tid] += add;
                __syncthreads();
            }
            if (tid < 256) {
                unsigned int ge = hist[tid];
                unsigned int gt = (tid < 255) ? hist[tid + 1] : 0u;
                if (ge >= (unsigned)krem && gt < (unsigned)krem) {
                    s_digit = tid; s_krem = krem - (int)gt;
                    if (ge == (unsigned)krem) s_done = 1;   // whole bin fills quota
                }
            }
            __syncthreads();
            prefix |= ((u64)s_digit) << shift;
            krem = s_krem;
            int done = s_done;
            __syncthreads();
            if (done) break;
        }
        // exactly 512 keys >= prefix (keys unique: low bits are ~idx)
        if (tid == 0) s_cnt = 0;
        __syncthreads();
        for (int i = tid; i < n; i += 1024) {
            u64 k = keys[i];
            if (k >= prefix) {
                unsigned int pos = atomicAdd(&s_cnt, 1u);
                if (pos < TOPK) skeys[pos] = k;
            }
        }
        __syncthreads();
        for (int i = (int)s_cnt + tid; i < TOPK; i += 1024) skeys[i] = 0ULL;
    } else {
        for (int i = tid; i < TOPK; i += 1024) skeys[i] = (i < n) ? keys[i] : 0ULL;
    }
    __syncthreads();

    if (s < BN) {
        // m==0: bitonic sort descending (exact lax.top_k order: val desc,
        // ties -> lower idx first since low bits are ~idx)
        for (int k = 2; k <= TOPK; k <<= 1) {
            for (int j = k >> 1; j > 0; j >>= 1) {
                if (tid < 256) {
                    int i = (tid % j) + (tid / j) * (j << 1);
                    int l = i + j;
                    bool desc = ((i & k) == 0);
                    u64 a = skeys[i], c = skeys[l];
                    if ((a < c) == desc) { skeys[i] = c; skeys[l] = a; }
                }
                __syncthreads();
            }
        }
    }

    for (int i = tid; i < TOPK; i += 1024) {
        u64 k = skeys[i];
        sel[(size_t)s * TOPK + i] = k;
        if (s < BN) {
            unsigned int idx = ~(unsigned int)(k & 0xFFFFFFFFULL);
            int y = (int)(idx / WW), x = (int)(idx - (unsigned int)y * WW);
            kp_out[(size_t)(s * TOPK + i) * 2 + 0] = (float)y;
            kp_out[(size_t)(s * TOPK + i) * 2 + 1] = (float)x;
        }
    }
}

// ============ kernel 4: gaussian stamp (15x15, sigma=0.5) ============
// normalized outer product = exp(-2*dy^2)*exp(-2*dx^2) / S^2, S = sum exp(-2k^2)
__global__ void k_stamp(const u64* __restrict__ sel,
                        float* __restrict__ maps) {
    int gi = blockIdx.x;                       // 0 .. 2*16*512-1
    u64 k = sel[gi];
    float val = __uint_as_float((unsigned int)(k >> 32));
    if (val <= 0.f) return;
    unsigned int idx = ~(unsigned int)(k & 0xFFFFFFFFULL);
    int py = (int)(idx / WW), px = (int)(idx - (unsigned int)py * WW);
    int t = threadIdx.x;
    if (t >= 225) return;
    int dy = t / 15 - 7, dx = t - (dy + 7) * 15 - 7;
    int yy = py + dy, xx = px + dx;
    if (yy < 0 || yy >= HH || xx < 0 || xx >= WW) return;
    const float inv_s2 = 0.61869347f;          // 1 / (sum exp(-2k^2))^2
    float ga = __expf(-2.f * (float)(dy * dy));
    float gb = __expf(-2.f * (float)(dx * dx));
    int m = gi >> 13, b = (gi >> 9) & 15;
    atomicAdd(&maps[((size_t)m * BN + b) * HWSZ + yy * WW + xx], val * ga * gb * inv_s2);
}

// ============ kernel 5: masked MSE partial reduction (no atomics) ============
// vis points into d_out at a 4-byte-aligned (not 16-byte) offset -> scalar loads.
__global__ void k_reduce(const float* __restrict__ maps,
                         const float* __restrict__ vis,
                         float* __restrict__ partial) {
    const int N = BN * HWSZ;
    float lp = 0.f, vsum = 0.f;
    int stride = RED_BLOCKS * 256 * 4;
    for (int i = (blockIdx.x * 256 + threadIdx.x) * 4; i < N; i += stride) {
        float4 m0 = *reinterpret_cast<const float4*>(maps + i);
        float4 m1 = *reinterpret_cast<const float4*>(maps + N + i);
        float v0 = vis[i + 0], v1 = vis[i + 1], v2 = vis[i + 2], v3 = vis[i + 3];
        float d0 = m0.x - m1.x, d1 = m0.y - m1.y, d2 = m0.z - m1.z, d3 = m0.w - m1.w;
        lp += d0 * d0 * v0 + d1 * d1 * v1 + d2 * d2 * v2 + d3 * d3 * v3;
        vsum += v0 + v1 + v2 + v3;
    }
    #pragma unroll
    for (int off = 32; off > 0; off >>= 1) {
        lp   += __shfl_down(lp, off);
        vsum += __shfl_down(vsum, off);
    }
    __shared__ float sl[4], sv[4];
    int w = threadIdx.x >> 6, ln = threadIdx.x & 63;
    if (ln == 0) { sl[w] = lp; sv[w] = vsum; }
    __syncthreads();
    if (threadIdx.x == 0) {
        partial[blockIdx.x * 2 + 0] = sl[0] + sl[1] + sl[2] + sl[3];
        partial[blockIdx.x * 2 + 1] = sv[0] + sv[1] + sv[2] + sv[3];
    }
}

__global__ void k_final(const float* __restrict__ partial, float* __restrict__ out) {
    float a = 0.f, c = 0.f;
    for (int i = threadIdx.x; i < RED_BLOCKS; i += 256) {
        a += partial[i * 2 + 0];
        c += partial[i * 2 + 1];
    }
    #pragma unroll
    for (int off = 32; off > 0; off >>= 1) {
        a += __shfl_down(a, off);
        c += __shfl_down(c, off);
    }
    __shared__ float sl[4], sv[4];
    int w = threadIdx.x >> 6, ln = threadIdx.x & 63;
    if (ln == 0) { sl[w] = a; sv[w] = c; }
    __syncthreads();
    if (threadIdx.x == 0)
        out[0] = (sl[0] + sl[1] + sl[2] + sl[3]) / (sv[0] + sv[1] + sv[2] + sv[3]);
}

extern "C" void kernel_launch(void* const* d_in, const int* in_sizes, int n_in,
                              void* d_out, int out_size, void* d_ws, size_t ws_size,
                              hipStream_t stream) {
    const float* score1 = (const float*)d_in[0];
    const float* score2 = (const float*)d_in[1];
    const float* homo   = (const float*)d_in[2];
    float* out = (float*)d_out;
    char* ws = (char*)d_ws;

    float* w2          = (float*)(ws + W2_OFF);
    float* maps        = (float*)(ws + MAPS_OFF);
    u64* cand          = (u64*)(ws + CAND_OFF);
    unsigned int* cnt  = (unsigned int*)(ws + CNT_OFF);
    u64* sel           = (u64*)(ws + SEL_OFF);
    float* partial     = (float*)(ws + PART_OFF);

    float* kp_out  = out + 1;
    float* vis_out = out + 1 + (size_t)BN * TOPK * 2;

    hipMemsetAsync(maps, 0, MAPS_SZ, stream);

    k_warp_vis<<<BN * HWSZ / (256 * 4), 256, 0, stream>>>(score2, homo, w2, vis_out, cnt);

    dim3 g(WW / NTX, HH / NTY, 2 * BN);
    k_nms<<<g, 256, 0, stream>>>(score1, w2, cand, cnt);

    k_topk<<<32, 1024, 0, stream>>>(cand, cnt, sel, kp_out);

    k_stamp<<<2 * BN * TOPK, 256, 0, stream>>>(sel, maps);

    k_reduce<<<RED_BLOCKS, 256, 0, stream>>>(maps, vis_out, partial);
    k_final<<<1, 256, 0, stream>>>(partial, out);
}

// Round 14
// 202.704 us; speedup vs baseline: 1.0668x; 1.0668x over previous
//
#include <hip/hip_runtime.h>
#include <cstdint>
#include <cstddef>

#define BN 16
#define HH 480
#define WW 640
#define HWSZ (HH*WW)
#define CAP 32768
#define TOPK 512
#define RED_BLOCKS 2048
#define NTX 64
#define NTY 32

typedef unsigned long long u64;

// ---- workspace layout (bytes) ----
#define W2_OFF   0ULL
#define W2_SZ    ((unsigned long long)BN*HWSZ*4ULL)            // 19,660,800
#define MAPS_OFF (W2_OFF + W2_SZ)
#define MAPS_SZ  (2ULL*BN*HWSZ*4ULL)                           // 39,321,600
#define CAND_OFF (MAPS_OFF + MAPS_SZ)
#define CAND_SZ  (2ULL*BN*CAP*8ULL)                            // 8,388,608
#define CNT_OFF  (CAND_OFF + CAND_SZ)
#define CNT_SZ   (4096ULL)                                     // 32 counters, 128B apart
#define SEL_OFF  (CNT_OFF + CNT_SZ)
#define SEL_SZ   (2ULL*BN*TOPK*8ULL)                           // 131,072
#define PART_OFF (SEL_OFF + SEL_SZ)
#define PART_SZ  ((unsigned long long)RED_BLOCKS*2*4ULL)       // 16,384

// ============ kernel 1: warp score2 (border-filtered) + visibility ============
// 4 px/thread; per-pixel math identical to the verified scalar version.
// Block 0 zeroes cnt[]; every thread zeroes its 8-float slice of maps
// (replaces two memset dispatches; k_nms/k_stamp launch strictly after).
__global__ void k_warp_vis(const float* __restrict__ score2,
                           const float* __restrict__ homo,
                           float* __restrict__ w2,
                           float* __restrict__ vis,
                           unsigned int* __restrict__ cnt,
                           float* __restrict__ maps) {
    if (blockIdx.x == 0) {
        for (int i = threadIdx.x; i < 1024; i += 256) cnt[i] = 0u;
    }
    int t = blockIdx.x * 256 + threadIdx.x;            // < BN*HWSZ/4
    // zero maps: 2*BN*HWSZ floats / (BN*HWSZ/4 threads) = 8 floats/thread
    {
        float4 z4 = make_float4(0.f, 0.f, 0.f, 0.f);
        *reinterpret_cast<float4*>(maps + (size_t)t * 8)     = z4;
        *reinterpret_cast<float4*>(maps + (size_t)t * 8 + 4) = z4;
    }
    int b = t / (HWSZ / 4);
    int q = t - b * (HWSZ / 4);
    int p = q * 4;                                     // 4-aligned, same row (WW%4==0)
    int py = p / WW, px = p - py * WW;
    const float* h = homo + b * 9;
    const float* sb = score2 + (size_t)b * HWSZ;

    float4 wout;
    float vout[4];
    #pragma unroll
    for (int u = 0; u < 4; ++u) {
        float fx = (float)(px + u), fy = (float)py;
        float X = h[0] * fx + h[1] * fy + h[2];
        float Y = h[3] * fx + h[4] * fy + h[5];
        float Z = h[6] * fx + h[7] * fy + h[8];
        float x = X / Z, y = Y / Z;
        float x0 = floorf(x), y0 = floorf(y);
        float wx = x - x0, wy = y - y0;
        float vv[4], gv[4];
        #pragma unroll
        for (int j = 0; j < 2; ++j) {
            #pragma unroll
            for (int i = 0; i < 2; ++i) {
                float xx = x0 + (float)i;
                float yy = y0 + (float)j;
                bool valid = (xx >= 0.f) && (xx <= (float)(WW - 1)) &&
                             (yy >= 0.f) && (yy <= (float)(HH - 1));
                int xi = (int)fminf(fmaxf(xx, 0.f), (float)(WW - 1));
                int yi = (int)fminf(fmaxf(yy, 0.f), (float)(HH - 1));
                float v = sb[yi * WW + xi];
                bool inb = (xi >= 8) && (xi < WW - 8) && (yi >= 8) && (yi < HH - 8);
                vv[j * 2 + i] = (valid && inb) ? v : 0.f;
                gv[j * 2 + i] = valid ? 1.f : 0.f;
            }
        }
        float w00 = (1.f - wy) * (1.f - wx), w01 = (1.f - wy) * wx;
        float w10 = wy * (1.f - wx),         w11 = wy * wx;
        float val = w00 * vv[0] + w01 * vv[1] + w10 * vv[2] + w11 * vv[3];
        float vsm = w00 * gv[0] + w01 * gv[1] + w10 * gv[2] + w11 * gv[3];
        ((float*)&wout)[u] = val;
        vout[u] = (vsm > 0.f) ? 1.f : 0.f;
    }
    int base = b * HWSZ + p;
    *reinterpret_cast<float4*>(w2 + base) = wout;      // w2 16B-aligned in ws
    // vis points into d_out at 4-mod-16 byte offset -> scalar stores
    vis[base + 0] = vout[0];
    vis[base + 1] = vout[1];
    vis[base + 2] = vout[2];
    vis[base + 3] = vout[3];
}

// ============ kernel 2: 5x5 NMS, 64x32 tile, separable max, 8 out/thread ====
// (R10 config: 18.5 KB LDS -> ~67% occupancy; 128x32 regressed to 31%, R11)
// z in [0,32): z<16 -> score1 image z; z>=16 -> w2 image z-16
__global__ void k_nms(const float* __restrict__ s1,
                      const float* __restrict__ w2,
                      u64* __restrict__ cand,
                      unsigned int* __restrict__ cnt) {
    __shared__ float tile[NTY + 4][NTX + 4];     // 36 x 68 = 9792 B
    __shared__ float colmax[NTY][NTX + 4];       // 32 x 68 = 8704 B
    __shared__ unsigned int s_loc, s_base;
    int z = blockIdx.z;
    const float* sb = (z < BN) ? (s1 + (size_t)z * HWSZ)
                               : (w2 + (size_t)(z - BN) * HWSZ);
    int tid = threadIdx.x;
    int bx0 = blockIdx.x * NTX, by0 = blockIdx.y * NTY;
    if (tid == 0) s_loc = 0;

    for (int i = tid; i < (NTY + 4) * (NTX + 4); i += 256) {
        int ly = i / (NTX + 4), lx = i - ly * (NTX + 4);
        int gy = by0 + ly - 2, gx = bx0 + lx - 2;
        float v = -__builtin_inff();
        if ((unsigned)gy < (unsigned)HH && (unsigned)gx < (unsigned)WW)
            v = sb[gy * WW + gx];
        tile[ly][lx] = v;
    }
    __syncthreads();

    // column max over 5 rows
    for (int i = tid; i < NTY * (NTX + 4); i += 256) {
        int y = i / (NTX + 4), x = i - y * (NTX + 4);
        float m = tile[y][x];
        m = fmaxf(m, tile[y + 1][x]);
        m = fmaxf(m, tile[y + 2][x]);
        m = fmaxf(m, tile[y + 3][x]);
        m = fmaxf(m, tile[y + 4][x]);
        colmax[y][x] = m;
    }
    __syncthreads();

    int ox = tid & 63, oyb = (tid >> 6) * 8;     // 4 waves x 8 rows = 32
    bool fl[8];
    float vv[8];
    unsigned int pos[8];
    #pragma unroll
    for (int k = 0; k < 8; ++k) {
        int oy = oyb + k;
        float v = tile[oy + 2][ox + 2];
        float m = colmax[oy][ox];
        m = fmaxf(m, colmax[oy][ox + 1]);
        m = fmaxf(m, colmax[oy][ox + 2]);
        m = fmaxf(m, colmax[oy][ox + 3]);
        m = fmaxf(m, colmax[oy][ox + 4]);
        fl[k] = (v == m) && (v > 0.f);
        vv[k] = v;
        if (fl[k]) pos[k] = atomicAdd(&s_loc, 1u);
    }
    __syncthreads();
    if (tid == 0 && s_loc) s_base = atomicAdd(&cnt[z * 32], s_loc);
    __syncthreads();
    #pragma unroll
    for (int k = 0; k < 8; ++k) {
        if (fl[k]) {
            unsigned int off = s_base + pos[k];
            if (off < CAP) {
                int p = (by0 + oyb + k) * WW + bx0 + ox;
                cand[(size_t)z * CAP + off] =
                    ((u64)__float_as_uint(vv[k]) << 32) | (u64)(~(unsigned)p);
            }
        }
    }
}

// ============ kernel 3: radix-select top-512; m==0 blocks also sort + emit kp
__global__ __launch_bounds__(1024) void k_topk(const u64* __restrict__ cand,
                                               const unsigned int* __restrict__ cnt,
                                               u64* __restrict__ sel,
                                               float* __restrict__ kp_out) {
    int s = blockIdx.x;                 // 0..31 : m = s>>4, b = s&15
    int tid = threadIdx.x;              // 1024 threads
    int n = (int)cnt[s * 32];
    if (n > CAP) n = CAP;
    const u64* keys = cand + (size_t)s * CAP;

    __shared__ unsigned int histw[16][256];   // per-wave histograms
    __shared__ unsigned int hist[256];
    __shared__ u64 skeys[TOPK];
    __shared__ int s_digit, s_krem, s_done;
    __shared__ unsigned int s_cnt;

    int wid = tid >> 6;

    if (n > TOPK) {
        u64 prefix = 0ULL;
        int krem = TOPK;
        for (int lvl = 7; lvl >= 0; --lvl) {
            for (int i = tid; i < 16 * 256; i += 1024) ((unsigned int*)histw)[i] = 0u;
            if (tid == 0) s_done = 0;
            __syncthreads();
            int shift = lvl * 8;
            u64 pmask = (lvl == 7) ? 0ULL : (~0ULL << (shift + 8));
            for (int i = tid; i < n; i += 1024) {
                u64 k = keys[i];
                if ((k & pmask) == prefix)
                    atomicAdd(&histw[wid][(unsigned int)((k >> shift) & 0xFF)], 1u);
            }
            __syncthreads();
            if (tid < 256) {
                unsigned int sum = 0;
                #pragma unroll
                for (int w = 0; w < 16; ++w) sum += histw[w][tid];
                hist[tid] = sum;
            }
            __syncthreads();
            // inclusive suffix-sum: hist[v] = count of digits >= v
            for (int off = 1; off < 256; off <<= 1) {
                unsigned int add = 0;
                if (tid < 256 - off) add = hist[tid + off];
                __syncthreads();
                if (tid < 256) hist[tid] += add;
                __syncthreads();
            }
            if (tid < 256) {
                unsigned int ge = hist[tid];
                unsigned int gt = (tid < 255) ? hist[tid + 1] : 0u;
                if (ge >= (unsigned)krem && gt < (unsigned)krem) {
                    s_digit = tid; s_krem = krem - (int)gt;
                    if (ge == (unsigned)krem) s_done = 1;   // whole bin fills quota
                }
            }
            __syncthreads();
            prefix |= ((u64)s_digit) << shift;
            krem = s_krem;
            int done = s_done;
            __syncthreads();
            if (done) break;
        }
        // exactly 512 keys >= prefix (keys unique: low bits are ~idx)
        if (tid == 0) s_cnt = 0;
        __syncthreads();
        for (int i = tid; i < n; i += 1024) {
            u64 k = keys[i];
            if (k >= prefix) {
                unsigned int pos = atomicAdd(&s_cnt, 1u);
                if (pos < TOPK) skeys[pos] = k;
            }
        }
        __syncthreads();
        for (int i = (int)s_cnt + tid; i < TOPK; i += 1024) skeys[i] = 0ULL;
    } else {
        for (int i = tid; i < TOPK; i += 1024) skeys[i] = (i < n) ? keys[i] : 0ULL;
    }
    __syncthreads();

    if (s < BN) {
        // m==0: bitonic sort descending (exact lax.top_k order: val desc,
        // ties -> lower idx first since low bits are ~idx)
        for (int k = 2; k <= TOPK; k <<= 1) {
            for (int j = k >> 1; j > 0; j >>= 1) {
                if (tid < 256) {
                    int i = (tid % j) + (tid / j) * (j << 1);
                    int l = i + j;
                    bool desc = ((i & k) == 0);
                    u64 a = skeys[i], c = skeys[l];
                    if ((a < c) == desc) { skeys[i] = c; skeys[l] = a; }
                }
                __syncthreads();
            }
        }
    }

    for (int i = tid; i < TOPK; i += 1024) {
        u64 k = skeys[i];
        sel[(size_t)s * TOPK + i] = k;
        if (s < BN) {
            unsigned int idx = ~(unsigned int)(k & 0xFFFFFFFFULL);
            int y = (int)(idx / WW), x = (int)(idx - (unsigned int)y * WW);
            kp_out[(size_t)(s * TOPK + i) * 2 + 0] = (float)y;
            kp_out[(size_t)(s * TOPK + i) * 2 + 1] = (float)x;
        }
    }
}

// ============ kernel 4: gaussian stamp (15x15, sigma=0.5), flat mapping =====
// normalized outer product = exp(-2*dy^2)*exp(-2*dx^2) / S^2, S = sum exp(-2k^2)
// thread -> (key gi, tap t); grid covers 2*BN*TOPK*225 threads exactly.
__global__ void k_stamp(const u64* __restrict__ sel,
                        float* __restrict__ maps) {
    int idx = blockIdx.x * 256 + threadIdx.x;  // < 2*BN*TOPK*225 = 3,686,400
    int gi = idx / 225;
    int t  = idx - gi * 225;
    u64 k = sel[gi];
    float val = __uint_as_float((unsigned int)(k >> 32));
    if (val <= 0.f) return;
    unsigned int pidx = ~(unsigned int)(k & 0xFFFFFFFFULL);
    int py = (int)(pidx / WW), px = (int)(pidx - (unsigned int)py * WW);
    int dy = t / 15 - 7, dx = t - (dy + 7) * 15 - 7;
    int yy = py + dy, xx = px + dx;
    if (yy < 0 || yy >= HH || xx < 0 || xx >= WW) return;
    const float inv_s2 = 0.61869347f;          // 1 / (sum exp(-2k^2))^2
    float ga = __expf(-2.f * (float)(dy * dy));
    float gb = __expf(-2.f * (float)(dx * dx));
    int m = gi >> 13, b = (gi >> 9) & 15;
    atomicAdd(&maps[((size_t)m * BN + b) * HWSZ + yy * WW + xx], val * ga * gb * inv_s2);
}

// ============ kernel 5: masked MSE partial reduction (no atomics) ============
// vis points into d_out at a 4-byte-aligned (not 16-byte) offset -> scalar loads.
__global__ void k_reduce(const float* __restrict__ maps,
                         const float* __restrict__ vis,
                         float* __restrict__ partial) {
    const int N = BN * HWSZ;
    float lp = 0.f, vsum = 0.f;
    int stride = RED_BLOCKS * 256 * 4;
    for (int i = (blockIdx.x * 256 + threadIdx.x) * 4; i < N; i += stride) {
        float4 m0 = *reinterpret_cast<const float4*>(maps + i);
        float4 m1 = *reinterpret_cast<const float4*>(maps + N + i);
        float v0 = vis[i + 0], v1 = vis[i + 1], v2 = vis[i + 2], v3 = vis[i + 3];
        float d0 = m0.x - m1.x, d1 = m0.y - m1.y, d2 = m0.z - m1.z, d3 = m0.w - m1.w;
        lp += d0 * d0 * v0 + d1 * d1 * v1 + d2 * d2 * v2 + d3 * d3 * v3;
        vsum += v0 + v1 + v2 + v3;
    }
    #pragma unroll
    for (int off = 32; off > 0; off >>= 1) {
        lp   += __shfl_down(lp, off);
        vsum += __shfl_down(vsum, off);
    }
    __shared__ float sl[4], sv[4];
    int w = threadIdx.x >> 6, ln = threadIdx.x & 63;
    if (ln == 0) { sl[w] = lp; sv[w] = vsum; }
    __syncthreads();
    if (threadIdx.x == 0) {
        partial[blockIdx.x * 2 + 0] = sl[0] + sl[1] + sl[2] + sl[3];
        partial[blockIdx.x * 2 + 1] = sv[0] + sv[1] + sv[2] + sv[3];
    }
}

__global__ void k_final(const float* __restrict__ partial, float* __restrict__ out) {
    float a = 0.f, c = 0.f;
    for (int i = threadIdx.x; i < RED_BLOCKS; i += 256) {
        a += partial[i * 2 + 0];
        c += partial[i * 2 + 1];
    }
    #pragma unroll
    for (int off = 32; off > 0; off >>= 1) {
        a += __shfl_down(a, off);
        c += __shfl_down(c, off);
    }
    __shared__ float sl[4], sv[4];
    int w = threadIdx.x >> 6, ln = threadIdx.x & 63;
    if (ln == 0) { sl[w] = a; sv[w] = c; }
    __syncthreads();
    if (threadIdx.x == 0)
        out[0] = (sl[0] + sl[1] + sl[2] + sl[3]) / (sv[0] + sv[1] + sv[2] + sv[3]);
}

extern "C" void kernel_launch(void* const* d_in, const int* in_sizes, int n_in,
                              void* d_out, int out_size, void* d_ws, size_t ws_size,
                              hipStream_t stream) {
    const float* score1 = (const float*)d_in[0];
    const float* score2 = (const float*)d_in[1];
    const float* homo   = (const float*)d_in[2];
    float* out = (float*)d_out;
    char* ws = (char*)d_ws;

    float* w2          = (float*)(ws + W2_OFF);
    float* maps        = (float*)(ws + MAPS_OFF);
    u64* cand          = (u64*)(ws + CAND_OFF);
    unsigned int* cnt  = (unsigned int*)(ws + CNT_OFF);
    u64* sel           = (u64*)(ws + SEL_OFF);
    float* partial     = (float*)(ws + PART_OFF);

    float* kp_out  = out + 1;
    float* vis_out = out + 1 + (size_t)BN * TOPK * 2;

    k_warp_vis<<<BN * HWSZ / (256 * 4), 256, 0, stream>>>(score2, homo, w2, vis_out, cnt, maps);

    dim3 g(WW / NTX, HH / NTY, 2 * BN);
    k_nms<<<g, 256, 0, stream>>>(score1, w2, cand, cnt);

    k_topk<<<32, 1024, 0, stream>>>(cand, cnt, sel, kp_out);

    k_stamp<<<(2 * BN * TOPK * 225) / 256, 256, 0, stream>>>(sel, maps);

    k_reduce<<<RED_BLOCKS, 256, 0, stream>>>(maps, vis_out, partial);
    k_final<<<1, 256, 0, stream>>>(partial, out);
}